// Round 2
// baseline (644.844 us; speedup 1.0000x reference)
//
#include <hip/hip_runtime.h>
#include <math.h>

constexpr int NN   = 20000;
constexpr int FM   = 128;
constexpr int NH   = 8;
constexpr int HF   = NH * FM;     // 1024
constexpr int EE   = 160000;
constexpr int ET   = EE + NN;     // 180000 (edges + self loops)
constexpr int OC   = 128;
constexpr int CIRC = 504;
constexpr int MIRN = NN - CIRC;   // 19496
constexpr float NEG = 0.2f;

constexpr size_t OFF_CIRC = (size_t)CIRC * MIRN;            // 9,825,984
constexpr size_t OFF_MIR  = OFF_CIRC + (size_t)CIRC * OC;   // 9,890,496

// ---------------- CSR build ----------------
__global__ void k_init_counts(int* __restrict__ cnt) {
  int i = blockIdx.x * blockDim.x + threadIdx.x;
  if (i < NN) cnt[i] = 1;  // self loop
}

__global__ void k_count(const int* __restrict__ ei, int* __restrict__ cnt) {
  int e = blockIdx.x * blockDim.x + threadIdx.x;
  if (e < EE) atomicAdd(&cnt[ei[EE + e]], 1);
}

__global__ __launch_bounds__(1024) void k_scan(const int* __restrict__ cnt,
                                               int* __restrict__ rs,
                                               int* __restrict__ cur) {
  __shared__ int part[1024];
  const int t = threadIdx.x;
  const int SEG = (NN + 1023) / 1024;  // 20
  int lo = t * SEG, hi = min(NN, lo + SEG);
  int s = 0;
  for (int i = lo; i < hi; ++i) s += cnt[i];
  part[t] = s;
  __syncthreads();
  for (int off = 1; off < 1024; off <<= 1) {
    int v = 0;
    if (t >= off) v = part[t - off];
    __syncthreads();
    part[t] += v;
    __syncthreads();
  }
  int run = (t == 0) ? 0 : part[t - 1];
  for (int i = lo; i < hi; ++i) {
    int c = cnt[i];
    rs[i] = run;
    cur[i] = run;
    run += c;
  }
  if (t == 1023) rs[NN] = part[1023];
}

__global__ void k_fill(const int* __restrict__ ei, int* __restrict__ cur,
                       int* __restrict__ csrc) {
  int i = blockIdx.x * blockDim.x + threadIdx.x;
  if (i >= ET) return;
  int s, d;
  if (i < EE) { s = ei[i]; d = ei[EE + i]; }
  else        { s = i - EE; d = s; }
  int p = atomicAdd(&cur[d], 1);
  csrc[p] = s;
}

// ---------------- h = X @ W  (M x 128 @ 128 x 1024) ----------------
// block tile 64 rows x 256 cols, 256 threads, 8x8 register blocking. LDS 33 KB.
__global__ __launch_bounds__(256) void k_gemm_xw(const float* __restrict__ X,
                                                 const float* __restrict__ W,
                                                 float* __restrict__ O, int M) {
  __shared__ float xs[64][129];  // pad 129: conflict-free broadcast reads
  const int t = threadIdx.x;
  const int row0 = blockIdx.x * 64;
  const int col0 = blockIdx.y * 256;
#pragma unroll
  for (int it = 0; it < 8; ++it) {
    int f4 = it * 256 + t;      // 2048 float4 = 64x128
    int r = f4 >> 5;
    int c = (f4 & 31) << 2;
    float4 v = make_float4(0.f, 0.f, 0.f, 0.f);
    int gr = row0 + r;
    if (gr < M) v = *reinterpret_cast<const float4*>(X + (size_t)gr * FM + c);
    xs[r][c] = v.x; xs[r][c + 1] = v.y; xs[r][c + 2] = v.z; xs[r][c + 3] = v.w;
  }
  __syncthreads();
  const int tr = (t >> 5) << 3;  // 8 row-groups of 8
  const int tc = (t & 31) << 3;  // 32 col-groups of 8
  float acc[8][8];
#pragma unroll
  for (int r = 0; r < 8; ++r)
#pragma unroll
    for (int c = 0; c < 8; ++c) acc[r][c] = 0.f;
  const float* Wp = W + col0 + tc;
  for (int kk = 0; kk < FM; ++kk) {
    float4 b0 = *reinterpret_cast<const float4*>(Wp + (size_t)kk * HF);
    float4 b1 = *reinterpret_cast<const float4*>(Wp + (size_t)kk * HF + 4);
    float bv[8] = {b0.x, b0.y, b0.z, b0.w, b1.x, b1.y, b1.z, b1.w};
    float av[8];
#pragma unroll
    for (int r = 0; r < 8; ++r) av[r] = xs[tr + r][kk];
#pragma unroll
    for (int r = 0; r < 8; ++r)
#pragma unroll
      for (int c = 0; c < 8; ++c) acc[r][c] += av[r] * bv[c];
  }
#pragma unroll
  for (int r = 0; r < 8; ++r) {
    int gr = row0 + tr + r;
    if (gr < M) {
      float4 o0 = make_float4(acc[r][0], acc[r][1], acc[r][2], acc[r][3]);
      float4 o1 = make_float4(acc[r][4], acc[r][5], acc[r][6], acc[r][7]);
      *reinterpret_cast<float4*>(O + (size_t)gr * HF + col0 + tc) = o0;
      *reinterpret_cast<float4*>(O + (size_t)gr * HF + col0 + tc + 4) = o1;
    }
  }
}

// ---------------- attention coefficients s,d ----------------
// one wave per (n,h): dot(h[n,h,:], a[h,:]) over 128
__global__ __launch_bounds__(256) void k_attn(const float* __restrict__ Hb,
                                              const float* __restrict__ Asc,
                                              const float* __restrict__ Adc,
                                              float* __restrict__ Sv,
                                              float* __restrict__ Dv) {
  const int wave = threadIdx.x >> 6;
  const int lane = threadIdx.x & 63;
  const int pair = blockIdx.x * 4 + wave;  // n*8+h
  if (pair >= NN * NH) return;
  const int hd = pair & 7;
  float2 hv  = *reinterpret_cast<const float2*>(Hb + (size_t)pair * FM + lane * 2);
  float2 a_s = *reinterpret_cast<const float2*>(Asc + hd * FM + lane * 2);
  float2 a_d = *reinterpret_cast<const float2*>(Adc + hd * FM + lane * 2);
  float sv = hv.x * a_s.x + hv.y * a_s.y;
  float dv = hv.x * a_d.x + hv.y * a_d.y;
#pragma unroll
  for (int m = 32; m >= 1; m >>= 1) {
    sv += __shfl_xor(sv, m, 64);
    dv += __shfl_xor(dv, m, 64);
  }
  if (lane == 0) { Sv[pair] = sv; Dv[pair] = dv; }
}

// ---------------- per-dst online-softmax aggregation ----------------
// one block (256 thr) per node; chunks of 32 edges; flash-style rescale
__global__ __launch_bounds__(256) void k_agg(const float* __restrict__ Hb,
                                             const float* __restrict__ Sv,
                                             const float* __restrict__ Dv,
                                             const int* __restrict__ rs,
                                             const int* __restrict__ csrc,
                                             const float* __restrict__ bias,
                                             float* __restrict__ Xo) {
  const int n = blockIdx.x;
  const int t = threadIdx.x;
  __shared__ float lbuf[32][8];
  __shared__ int   srcb[32];
  __shared__ float mS[8], lS[8], fS[8];
  __shared__ float comb[128];
  if (t < 8) { mS[t] = -INFINITY; lS[t] = 0.f; }
  const int r0 = rs[n];
  const int deg = rs[n + 1] - r0;
  const int f  = t & 127;
  const int hg = t >> 7;  // 0: heads 0-3, 1: heads 4-7
  float acc[4] = {0.f, 0.f, 0.f, 0.f};
  __syncthreads();
  for (int base = 0; base < deg; base += 32) {
    const int cnt = min(32, deg - base);
    if (t < cnt) srcb[t] = csrc[r0 + base + t];
    __syncthreads();
    const int j = t >> 3, hd = t & 7;
    if (j < cnt) {
      float lg = Sv[srcb[j] * 8 + hd] + Dv[n * 8 + hd];
      lg = lg > 0.f ? lg : NEG * lg;
      lbuf[j][hd] = lg;
    }
    __syncthreads();
    if (t < 8) {
      float cm = -INFINITY;
      for (int jj = 0; jj < cnt; ++jj) cm = fmaxf(cm, lbuf[jj][t]);
      float mo = mS[t];
      float mn = fmaxf(mo, cm);
      mS[t] = mn;
      fS[t] = expf(mo - mn);  // first chunk: exp(-inf)=0, scales empty state
    }
    __syncthreads();
    if (j < cnt) lbuf[j][hd] = expf(lbuf[j][hd] - mS[hd]);
    __syncthreads();
    if (t < 8) {  // runs concurrently with aggregation below (disjoint arrays)
      float cs = 0.f;
      for (int jj = 0; jj < cnt; ++jj) cs += lbuf[jj][t];
      lS[t] = lS[t] * fS[t] + cs;
    }
#pragma unroll
    for (int c = 0; c < 4; ++c) acc[c] *= fS[hg * 4 + c];
    for (int jj = 0; jj < cnt; ++jj) {
      const float* hp = Hb + (size_t)srcb[jj] * HF + (hg * 4) * FM + f;
      float p0 = lbuf[jj][hg * 4 + 0];
      float p1 = lbuf[jj][hg * 4 + 1];
      float p2 = lbuf[jj][hg * 4 + 2];
      float p3 = lbuf[jj][hg * 4 + 3];
      acc[0] += p0 * hp[0];
      acc[1] += p1 * hp[FM];
      acc[2] += p2 * hp[2 * FM];
      acc[3] += p3 * hp[3 * FM];
    }
    __syncthreads();
  }
  float sum = 0.f;
#pragma unroll
  for (int c = 0; c < 4; ++c) sum += acc[c] / (lS[hg * 4 + c] + 1e-16f);
  if (hg == 1) comb[f] = sum;
  __syncthreads();
  if (hg == 0) {
    float v = (sum + comb[f]) * 0.125f + bias[f];
    Xo[(size_t)n * FM + f] = fmaxf(v, 0.f);  // both layers are relu'd
  }
}

// ---------------- Wc transpose: WcT[c*128+k][o] = Wc[o][c][k] ----------------
__global__ void k_transpose_wc(const float* __restrict__ Wc, float* __restrict__ WcT) {
  int i = blockIdx.x * blockDim.x + threadIdx.x;
  if (i < OC * 2 * FM) {
    int o = i / (2 * FM), k = i % (2 * FM);
    WcT[k * OC + o] = Wc[i];
  }
}

// ---------------- emb = [x1|x2] @ WcT + bc; write circ/mir slices of out ----
// two K-halves (X1 then X2) through one 33 KB padded LDS tile
__global__ __launch_bounds__(256) void k_emb(const float* __restrict__ X1,
                                             const float* __restrict__ X2,
                                             const float* __restrict__ WcT,
                                             const float* __restrict__ bc,
                                             float* __restrict__ Out) {
  __shared__ float xs[64][129];
  const int t = threadIdx.x;
  const int row0 = blockIdx.x * 64;
  const int tr = (t >> 5) << 3;  // 8 rows
  const int tc = (t & 31) << 2;  // 4 cols
  float acc[8][4] = {};
  for (int half = 0; half < 2; ++half) {
    const float* Xs = half ? X2 : X1;
    __syncthreads();  // protect xs reuse across halves
#pragma unroll
    for (int it = 0; it < 8; ++it) {
      int f4 = it * 256 + t;  // 2048 float4 = 64 x 128
      int r = f4 >> 5;
      int c = (f4 & 31) << 2;
      int gr = row0 + r;
      float4 v = make_float4(0.f, 0.f, 0.f, 0.f);
      if (gr < NN) v = *reinterpret_cast<const float4*>(Xs + (size_t)gr * FM + c);
      xs[r][c] = v.x; xs[r][c + 1] = v.y; xs[r][c + 2] = v.z; xs[r][c + 3] = v.w;
    }
    __syncthreads();
    const float* Wp = WcT + (size_t)half * FM * OC;
    for (int kk = 0; kk < FM; ++kk) {
      float4 b = *reinterpret_cast<const float4*>(Wp + kk * OC + tc);
      float av[8];
#pragma unroll
      for (int r = 0; r < 8; ++r) av[r] = xs[tr + r][kk];
#pragma unroll
      for (int r = 0; r < 8; ++r) {
        acc[r][0] += av[r] * b.x;
        acc[r][1] += av[r] * b.y;
        acc[r][2] += av[r] * b.z;
        acc[r][3] += av[r] * b.w;
      }
    }
  }
  float4 bcv = *reinterpret_cast<const float4*>(bc + tc);
#pragma unroll
  for (int r = 0; r < 8; ++r) {
    int gr = row0 + tr + r;
    if (gr < NN) {
      float4 o;
      o.x = acc[r][0] + bcv.x;
      o.y = acc[r][1] + bcv.y;
      o.z = acc[r][2] + bcv.z;
      o.w = acc[r][3] + bcv.w;
      float* dst = (gr < CIRC)
                       ? (Out + OFF_CIRC + (size_t)gr * OC + tc)
                       : (Out + OFF_MIR + (size_t)(gr - CIRC) * OC + tc);
      *reinterpret_cast<float4*>(dst) = o;
    }
  }
}

// ---------------- out1 = circ @ mir.T (504 x 19496, K=128) ----------------
// two K-halves of 64 through padded 64x65 tiles (2 x 16.6 KB LDS)
__global__ __launch_bounds__(256) void k_outer(const float* __restrict__ A,
                                               const float* __restrict__ B,
                                               float* __restrict__ C) {
  __shared__ float As[64][65];
  __shared__ float Bs[64][65];
  const int t = threadIdx.x;
  const int i0 = blockIdx.y * 64;
  const int j0 = blockIdx.x * 64;
  const int tx = t & 15, ty = t >> 4;
  float acc[4][4] = {};
  for (int kh = 0; kh < 2; ++kh) {
    __syncthreads();
#pragma unroll
    for (int it = 0; it < 4; ++it) {
      int f4 = it * 256 + t;   // 1024 float4 = 64 rows x 16
      int r = f4 >> 4;
      int c = (f4 & 15) << 2;
      float4 v = make_float4(0.f, 0.f, 0.f, 0.f);
      if (i0 + r < CIRC)
        v = *reinterpret_cast<const float4*>(A + (size_t)(i0 + r) * OC + kh * 64 + c);
      As[r][c] = v.x; As[r][c + 1] = v.y; As[r][c + 2] = v.z; As[r][c + 3] = v.w;
      float4 w = make_float4(0.f, 0.f, 0.f, 0.f);
      if (j0 + r < MIRN)
        w = *reinterpret_cast<const float4*>(B + (size_t)(j0 + r) * OC + kh * 64 + c);
      Bs[r][c] = w.x; Bs[r][c + 1] = w.y; Bs[r][c + 2] = w.z; Bs[r][c + 3] = w.w;
    }
    __syncthreads();
    for (int kk = 0; kk < 64; ++kk) {
      float a[4], b[4];
#pragma unroll
      for (int r = 0; r < 4; ++r) a[r] = As[ty * 4 + r][kk];
#pragma unroll
      for (int c = 0; c < 4; ++c) b[c] = Bs[tx * 4 + c][kk];
#pragma unroll
      for (int r = 0; r < 4; ++r)
#pragma unroll
        for (int c = 0; c < 4; ++c) acc[r][c] += a[r] * b[c];
    }
  }
#pragma unroll
  for (int r = 0; r < 4; ++r) {
    int i = i0 + ty * 4 + r;
    if (i >= CIRC) break;
#pragma unroll
    for (int c = 0; c < 4; ++c) {
      int j = j0 + tx * 4 + c;
      if (j < MIRN) C[(size_t)i * MIRN + j] = acc[r][c];
    }
  }
}

// ---------------- launcher ----------------
static inline size_t alignup(size_t v) { return (v + 255) & ~(size_t)255; }

extern "C" void kernel_launch(void* const* d_in, const int* in_sizes, int n_in,
                              void* d_out, int out_size, void* d_ws, size_t ws_size,
                              hipStream_t stream) {
  const float* x   = (const float*)d_in[0];
  const int*   ei  = (const int*)d_in[1];
  const float* W1  = (const float*)d_in[2];
  const float* as1 = (const float*)d_in[3];
  const float* ad1 = (const float*)d_in[4];
  const float* b1  = (const float*)d_in[5];
  const float* W2  = (const float*)d_in[6];
  const float* as2 = (const float*)d_in[7];
  const float* ad2 = (const float*)d_in[8];
  const float* b2  = (const float*)d_in[9];
  const float* Wc  = (const float*)d_in[10];
  const float* bc  = (const float*)d_in[11];
  float* out = (float*)d_out;

  char* w = (char*)d_ws;
  size_t off = 0;
  float* Hbuf = (float*)(w + off); off = alignup(off + (size_t)NN * HF * 4);
  float* Sbuf = (float*)(w + off); off = alignup(off + (size_t)NN * NH * 4);
  float* Dbuf = (float*)(w + off); off = alignup(off + (size_t)NN * NH * 4);
  float* X1   = (float*)(w + off); off = alignup(off + (size_t)NN * FM * 4);
  float* X2   = (float*)(w + off); off = alignup(off + (size_t)NN * FM * 4);
  float* WcT  = (float*)(w + off); off = alignup(off + (size_t)OC * 2 * FM * 4);
  int* counts = (int*)(w + off);   off = alignup(off + (size_t)NN * 4);
  int* rowst  = (int*)(w + off);   off = alignup(off + (size_t)(NN + 1) * 4);
  int* cursor = (int*)(w + off);   off = alignup(off + (size_t)NN * 4);
  int* csrsrc = (int*)(w + off);   off = alignup(off + (size_t)ET * 4);

  // CSR by dst (rebuilt every call; ws is re-poisoned)
  k_init_counts<<<(NN + 255) / 256, 256, 0, stream>>>(counts);
  k_count<<<(EE + 255) / 256, 256, 0, stream>>>(ei, counts);
  k_scan<<<1, 1024, 0, stream>>>(counts, rowst, cursor);
  k_fill<<<(ET + 255) / 256, 256, 0, stream>>>(ei, cursor, csrsrc);

  dim3 gGemm((NN + 63) / 64, HF / 256);
  // layer 1
  k_gemm_xw<<<gGemm, 256, 0, stream>>>(x, W1, Hbuf, NN);
  k_attn<<<NN * NH / 4, 256, 0, stream>>>(Hbuf, as1, ad1, Sbuf, Dbuf);
  k_agg<<<NN, 256, 0, stream>>>(Hbuf, Sbuf, Dbuf, rowst, csrsrc, b1, X1);
  // layer 2
  k_gemm_xw<<<gGemm, 256, 0, stream>>>(X1, W2, Hbuf, NN);
  k_attn<<<NN * NH / 4, 256, 0, stream>>>(Hbuf, as2, ad2, Sbuf, Dbuf);
  k_agg<<<NN, 256, 0, stream>>>(Hbuf, Sbuf, Dbuf, rowst, csrsrc, b2, X2);
  // classifier + outputs
  k_transpose_wc<<<(OC * 2 * FM + 255) / 256, 256, 0, stream>>>(Wc, WcT);
  k_emb<<<(NN + 63) / 64, 256, 0, stream>>>(X1, X2, WcT, bc, out);
  k_outer<<<dim3((MIRN + 63) / 64, (CIRC + 63) / 64), 256, 0, stream>>>(
      out + OFF_CIRC, out + OFF_MIR, out);
}

// Round 3
// 643.831 us; speedup vs baseline: 1.0016x; 1.0016x over previous
//
#include <hip/hip_runtime.h>
#include <math.h>

constexpr int NN   = 20000;
constexpr int FM   = 128;
constexpr int NH   = 8;
constexpr int HF   = NH * FM;     // 1024
constexpr int EE   = 160000;
constexpr int ET   = EE + NN;     // 180000 (edges + self loops)
constexpr int OC   = 128;
constexpr int CIRC = 504;
constexpr int MIRN = NN - CIRC;   // 19496
constexpr float NEG = 0.2f;

constexpr size_t OFF_CIRC = (size_t)CIRC * MIRN;            // 9,825,984
constexpr size_t OFF_MIR  = OFF_CIRC + (size_t)CIRC * OC;   // 9,890,496

__device__ __forceinline__ float rl_f(float v, int lane) {
  return __uint_as_float(__builtin_amdgcn_readlane(__float_as_uint(v), lane));
}
__device__ __forceinline__ int rl_i(int v, int lane) {
  return __builtin_amdgcn_readlane(v, lane);
}

// ---------------- CSR build ----------------
__global__ void k_init_counts(int* __restrict__ cnt) {
  int i = blockIdx.x * blockDim.x + threadIdx.x;
  if (i < NN) cnt[i] = 1;  // self loop
}

__global__ void k_count(const int* __restrict__ ei, int* __restrict__ cnt) {
  int e = blockIdx.x * blockDim.x + threadIdx.x;
  if (e < EE) atomicAdd(&cnt[ei[EE + e]], 1);
}

__global__ __launch_bounds__(1024) void k_scan(const int* __restrict__ cnt,
                                               int* __restrict__ rs,
                                               int* __restrict__ cur) {
  __shared__ int part[1024];
  const int t = threadIdx.x;
  const int SEG = (NN + 1023) / 1024;  // 20
  int lo = t * SEG, hi = min(NN, lo + SEG);
  int s = 0;
  for (int i = lo; i < hi; ++i) s += cnt[i];
  part[t] = s;
  __syncthreads();
  for (int off = 1; off < 1024; off <<= 1) {
    int v = 0;
    if (t >= off) v = part[t - off];
    __syncthreads();
    part[t] += v;
    __syncthreads();
  }
  int run = (t == 0) ? 0 : part[t - 1];
  for (int i = lo; i < hi; ++i) {
    int c = cnt[i];
    rs[i] = run;
    cur[i] = run;
    run += c;
  }
  if (t == 1023) rs[NN] = part[1023];
}

__global__ void k_fill(const int* __restrict__ ei, int* __restrict__ cur,
                       int* __restrict__ csrc) {
  int i = blockIdx.x * blockDim.x + threadIdx.x;
  if (i >= ET) return;
  int s, d;
  if (i < EE) { s = ei[i]; d = ei[EE + i]; }
  else        { s = i - EE; d = s; }
  int p = atomicAdd(&cur[d], 1);
  csrc[p] = s;
}

// ---------------- h = X @ W  (M x 128 @ 128 x 1024) ----------------
// block tile 64 rows x 256 cols, 256 threads, 8x8 register blocking. LDS 33 KB.
__global__ __launch_bounds__(256) void k_gemm_xw(const float* __restrict__ X,
                                                 const float* __restrict__ W,
                                                 float* __restrict__ O, int M) {
  __shared__ float xs[64][129];  // pad 129: conflict-free broadcast reads
  const int t = threadIdx.x;
  const int row0 = blockIdx.x * 64;
  const int col0 = blockIdx.y * 256;
#pragma unroll
  for (int it = 0; it < 8; ++it) {
    int f4 = it * 256 + t;      // 2048 float4 = 64x128
    int r = f4 >> 5;
    int c = (f4 & 31) << 2;
    float4 v = make_float4(0.f, 0.f, 0.f, 0.f);
    int gr = row0 + r;
    if (gr < M) v = *reinterpret_cast<const float4*>(X + (size_t)gr * FM + c);
    xs[r][c] = v.x; xs[r][c + 1] = v.y; xs[r][c + 2] = v.z; xs[r][c + 3] = v.w;
  }
  __syncthreads();
  const int tr = (t >> 5) << 3;  // 8 row-groups of 8
  const int tc = (t & 31) << 3;  // 32 col-groups of 8
  float acc[8][8];
#pragma unroll
  for (int r = 0; r < 8; ++r)
#pragma unroll
    for (int c = 0; c < 8; ++c) acc[r][c] = 0.f;
  const float* Wp = W + col0 + tc;
  for (int kk = 0; kk < FM; ++kk) {
    float4 b0 = *reinterpret_cast<const float4*>(Wp + (size_t)kk * HF);
    float4 b1 = *reinterpret_cast<const float4*>(Wp + (size_t)kk * HF + 4);
    float bv[8] = {b0.x, b0.y, b0.z, b0.w, b1.x, b1.y, b1.z, b1.w};
    float av[8];
#pragma unroll
    for (int r = 0; r < 8; ++r) av[r] = xs[tr + r][kk];
#pragma unroll
    for (int r = 0; r < 8; ++r)
#pragma unroll
      for (int c = 0; c < 8; ++c) acc[r][c] += av[r] * bv[c];
  }
#pragma unroll
  for (int r = 0; r < 8; ++r) {
    int gr = row0 + tr + r;
    if (gr < M) {
      float4 o0 = make_float4(acc[r][0], acc[r][1], acc[r][2], acc[r][3]);
      float4 o1 = make_float4(acc[r][4], acc[r][5], acc[r][6], acc[r][7]);
      *reinterpret_cast<float4*>(O + (size_t)gr * HF + col0 + tc) = o0;
      *reinterpret_cast<float4*>(O + (size_t)gr * HF + col0 + tc + 4) = o1;
    }
  }
}

// ---------------- attention coefficients s,d ----------------
__global__ __launch_bounds__(256) void k_attn(const float* __restrict__ Hb,
                                              const float* __restrict__ Asc,
                                              const float* __restrict__ Adc,
                                              float* __restrict__ Sv,
                                              float* __restrict__ Dv) {
  const int wave = threadIdx.x >> 6;
  const int lane = threadIdx.x & 63;
  const int pair = blockIdx.x * 4 + wave;  // n*8+h
  if (pair >= NN * NH) return;
  const int hd = pair & 7;
  float2 hv  = *reinterpret_cast<const float2*>(Hb + (size_t)pair * FM + lane * 2);
  float2 a_s = *reinterpret_cast<const float2*>(Asc + hd * FM + lane * 2);
  float2 a_d = *reinterpret_cast<const float2*>(Adc + hd * FM + lane * 2);
  float sv = hv.x * a_s.x + hv.y * a_s.y;
  float dv = hv.x * a_d.x + hv.y * a_d.y;
#pragma unroll
  for (int m = 32; m >= 1; m >>= 1) {
    sv += __shfl_xor(sv, m, 64);
    dv += __shfl_xor(dv, m, 64);
  }
  if (lane == 0) { Sv[pair] = sv; Dv[pair] = dv; }
}

// ---------------- per-dst online-softmax aggregation (1 wave / node) -------
// lane = (edge j = lane>>3, head h = lane&7) in softmax phase;
// gather: 4 float4/lane per edge (full 8-head row), readlane broadcasts.
__global__ __launch_bounds__(256) void k_agg(const float* __restrict__ Hb,
                                             const float* __restrict__ Sv,
                                             const float* __restrict__ Dv,
                                             const int* __restrict__ rs,
                                             const int* __restrict__ csrc,
                                             const float* __restrict__ bias,
                                             float* __restrict__ Xo) {
  const int wave = threadIdx.x >> 6;
  const int lane = threadIdx.x & 63;
  const int n = blockIdx.x * 4 + wave;
  if (n >= NN) return;
  const int r0 = rs[n];
  const int deg = rs[n + 1] - r0;   // >= 1 (self loop)
  const int j = lane >> 3, h = lane & 7;
  const int hi = lane >> 5;         // 0: lanes 0-31, 1: lanes 32-63
  const float dvh = Dv[n * 8 + h];

  float m = -INFINITY, l = 0.f;
  float4 acc[4];
#pragma unroll
  for (int q = 0; q < 4; ++q) acc[q] = make_float4(0.f, 0.f, 0.f, 0.f);

  for (int base = 0; base < deg; base += 8) {
    const int cnt = deg - base;  // >=1; active edges this chunk = min(8,cnt)
    int idxc = r0 + min(base + j, deg - 1);
    int sj = csrc[idxc];
    float lg = (j < cnt) ? (Sv[sj * 8 + h] + dvh) : -INFINITY;
    lg = lg > 0.f ? lg : NEG * lg;
    // chunk max over 8 edge-slots (xor 8/16/32 folds j, keeps h)
    float cm = lg;
    cm = fmaxf(cm, __shfl_xor(cm, 8, 64));
    cm = fmaxf(cm, __shfl_xor(cm, 16, 64));
    cm = fmaxf(cm, __shfl_xor(cm, 32, 64));
    float mn = fmaxf(m, cm);
    float fs = expf(m - mn);     // first chunk: exp(-inf)=0
    float p = expf(lg - mn);     // inactive: exp(-inf)=0
    float cs = p;
    cs += __shfl_xor(cs, 8, 64);
    cs += __shfl_xor(cs, 16, 64);
    cs += __shfl_xor(cs, 32, 64);
    l = l * fs + cs;
    m = mn;
    // rescale accumulators (per-head factor)
#pragma unroll
    for (int q = 0; q < 4; ++q) {
      float fA = rl_f(fs, 2 * q);
      float fB = rl_f(fs, 2 * q + 1);
      float f = hi ? fB : fA;
      acc[q].x *= f; acc[q].y *= f; acc[q].z *= f; acc[q].w *= f;
    }
    // gather: per edge, lanes 0-31 read head 2q, lanes 32-63 head 2q+1
#pragma unroll
    for (int jj = 0; jj < 8; ++jj) {
      if (jj < cnt) {
        int se = rl_i(sj, jj * 8);
        const float* hrow = Hb + (size_t)se * HF + hi * FM + (lane & 31) * 4;
#pragma unroll
        for (int q = 0; q < 4; ++q) {
          float pA = rl_f(p, jj * 8 + 2 * q);
          float pB = rl_f(p, jj * 8 + 2 * q + 1);
          float pe = hi ? pB : pA;
          float4 hv = *reinterpret_cast<const float4*>(hrow + q * 2 * FM);
          acc[q].x += pe * hv.x; acc[q].y += pe * hv.y;
          acc[q].z += pe * hv.z; acc[q].w += pe * hv.w;
        }
      }
    }
  }
  // divide by per-head denom, mean over heads
  float4 sum = make_float4(0.f, 0.f, 0.f, 0.f);
#pragma unroll
  for (int q = 0; q < 4; ++q) {
    float lA = rl_f(l, 2 * q);
    float lB = rl_f(l, 2 * q + 1);
    float inv = 1.0f / ((hi ? lB : lA) + 1e-16f);
    sum.x += acc[q].x * inv; sum.y += acc[q].y * inv;
    sum.z += acc[q].z * inv; sum.w += acc[q].w * inv;
  }
  sum.x += __shfl_xor(sum.x, 32, 64);
  sum.y += __shfl_xor(sum.y, 32, 64);
  sum.z += __shfl_xor(sum.z, 32, 64);
  sum.w += __shfl_xor(sum.w, 32, 64);
  if (lane < 32) {
    const int f0 = lane * 4;
    float4 bv = *reinterpret_cast<const float4*>(bias + f0);
    float4 o;
    o.x = fmaxf(sum.x * 0.125f + bv.x, 0.f);
    o.y = fmaxf(sum.y * 0.125f + bv.y, 0.f);
    o.z = fmaxf(sum.z * 0.125f + bv.z, 0.f);
    o.w = fmaxf(sum.w * 0.125f + bv.w, 0.f);
    *reinterpret_cast<float4*>(Xo + (size_t)n * FM + f0) = o;
  }
}

// ---------------- Wc transpose: WcT[c*128+k][o] = Wc[o][c][k] ----------------
__global__ void k_transpose_wc(const float* __restrict__ Wc, float* __restrict__ WcT) {
  int i = blockIdx.x * blockDim.x + threadIdx.x;
  if (i < OC * 2 * FM) {
    int o = i / (2 * FM), k = i % (2 * FM);
    WcT[k * OC + o] = Wc[i];
  }
}

// ---------------- emb = [x1|x2] @ WcT + bc; write circ/mir slices of out ----
__global__ __launch_bounds__(256) void k_emb(const float* __restrict__ X1,
                                             const float* __restrict__ X2,
                                             const float* __restrict__ WcT,
                                             const float* __restrict__ bc,
                                             float* __restrict__ Out) {
  __shared__ float xs[64][129];
  const int t = threadIdx.x;
  const int row0 = blockIdx.x * 64;
  const int tr = (t >> 5) << 3;  // 8 rows
  const int tc = (t & 31) << 2;  // 4 cols
  float acc[8][4] = {};
  for (int half = 0; half < 2; ++half) {
    const float* Xs = half ? X2 : X1;
    __syncthreads();  // protect xs reuse across halves
#pragma unroll
    for (int it = 0; it < 8; ++it) {
      int f4 = it * 256 + t;  // 2048 float4 = 64 x 128
      int r = f4 >> 5;
      int c = (f4 & 31) << 2;
      int gr = row0 + r;
      float4 v = make_float4(0.f, 0.f, 0.f, 0.f);
      if (gr < NN) v = *reinterpret_cast<const float4*>(Xs + (size_t)gr * FM + c);
      xs[r][c] = v.x; xs[r][c + 1] = v.y; xs[r][c + 2] = v.z; xs[r][c + 3] = v.w;
    }
    __syncthreads();
    const float* Wp = WcT + (size_t)half * FM * OC;
    for (int kk = 0; kk < FM; ++kk) {
      float4 b = *reinterpret_cast<const float4*>(Wp + kk * OC + tc);
      float av[8];
#pragma unroll
      for (int r = 0; r < 8; ++r) av[r] = xs[tr + r][kk];
#pragma unroll
      for (int r = 0; r < 8; ++r) {
        acc[r][0] += av[r] * b.x;
        acc[r][1] += av[r] * b.y;
        acc[r][2] += av[r] * b.z;
        acc[r][3] += av[r] * b.w;
      }
    }
  }
  float4 bcv = *reinterpret_cast<const float4*>(bc + tc);
#pragma unroll
  for (int r = 0; r < 8; ++r) {
    int gr = row0 + tr + r;
    if (gr < NN) {
      float4 o;
      o.x = acc[r][0] + bcv.x;
      o.y = acc[r][1] + bcv.y;
      o.z = acc[r][2] + bcv.z;
      o.w = acc[r][3] + bcv.w;
      float* dst = (gr < CIRC)
                       ? (Out + OFF_CIRC + (size_t)gr * OC + tc)
                       : (Out + OFF_MIR + (size_t)(gr - CIRC) * OC + tc);
      *reinterpret_cast<float4*>(dst) = o;
    }
  }
}

// ---------------- out1 = circ @ mir.T (504 x 19496, K=128) ----------------
__global__ __launch_bounds__(256) void k_outer(const float* __restrict__ A,
                                               const float* __restrict__ B,
                                               float* __restrict__ C) {
  __shared__ float As[64][65];
  __shared__ float Bs[64][65];
  const int t = threadIdx.x;
  const int i0 = blockIdx.y * 64;
  const int j0 = blockIdx.x * 64;
  const int tx = t & 15, ty = t >> 4;
  float acc[4][4] = {};
  for (int kh = 0; kh < 2; ++kh) {
    __syncthreads();
#pragma unroll
    for (int it = 0; it < 4; ++it) {
      int f4 = it * 256 + t;   // 1024 float4 = 64 rows x 16
      int r = f4 >> 4;
      int c = (f4 & 15) << 2;
      float4 v = make_float4(0.f, 0.f, 0.f, 0.f);
      if (i0 + r < CIRC)
        v = *reinterpret_cast<const float4*>(A + (size_t)(i0 + r) * OC + kh * 64 + c);
      As[r][c] = v.x; As[r][c + 1] = v.y; As[r][c + 2] = v.z; As[r][c + 3] = v.w;
      float4 w = make_float4(0.f, 0.f, 0.f, 0.f);
      if (j0 + r < MIRN)
        w = *reinterpret_cast<const float4*>(B + (size_t)(j0 + r) * OC + kh * 64 + c);
      Bs[r][c] = w.x; Bs[r][c + 1] = w.y; Bs[r][c + 2] = w.z; Bs[r][c + 3] = w.w;
    }
    __syncthreads();
    for (int kk = 0; kk < 64; ++kk) {
      float a[4], b[4];
#pragma unroll
      for (int r = 0; r < 4; ++r) a[r] = As[ty * 4 + r][kk];
#pragma unroll
      for (int c = 0; c < 4; ++c) b[c] = Bs[tx * 4 + c][kk];
#pragma unroll
      for (int r = 0; r < 4; ++r)
#pragma unroll
        for (int c = 0; c < 4; ++c) acc[r][c] += a[r] * b[c];
    }
  }
#pragma unroll
  for (int r = 0; r < 4; ++r) {
    int i = i0 + ty * 4 + r;
    if (i >= CIRC) break;
#pragma unroll
    for (int c = 0; c < 4; ++c) {
      int j = j0 + tx * 4 + c;
      if (j < MIRN) C[(size_t)i * MIRN + j] = acc[r][c];
    }
  }
}

// ---------------- launcher ----------------
static inline size_t alignup(size_t v) { return (v + 255) & ~(size_t)255; }

extern "C" void kernel_launch(void* const* d_in, const int* in_sizes, int n_in,
                              void* d_out, int out_size, void* d_ws, size_t ws_size,
                              hipStream_t stream) {
  const float* x   = (const float*)d_in[0];
  const int*   ei  = (const int*)d_in[1];
  const float* W1  = (const float*)d_in[2];
  const float* as1 = (const float*)d_in[3];
  const float* ad1 = (const float*)d_in[4];
  const float* b1  = (const float*)d_in[5];
  const float* W2  = (const float*)d_in[6];
  const float* as2 = (const float*)d_in[7];
  const float* ad2 = (const float*)d_in[8];
  const float* b2  = (const float*)d_in[9];
  const float* Wc  = (const float*)d_in[10];
  const float* bc  = (const float*)d_in[11];
  float* out = (float*)d_out;

  char* w = (char*)d_ws;
  size_t off = 0;
  float* Hbuf = (float*)(w + off); off = alignup(off + (size_t)NN * HF * 4);
  float* Sbuf = (float*)(w + off); off = alignup(off + (size_t)NN * NH * 4);
  float* Dbuf = (float*)(w + off); off = alignup(off + (size_t)NN * NH * 4);
  float* X1   = (float*)(w + off); off = alignup(off + (size_t)NN * FM * 4);
  float* X2   = (float*)(w + off); off = alignup(off + (size_t)NN * FM * 4);
  float* WcT  = (float*)(w + off); off = alignup(off + (size_t)OC * 2 * FM * 4);
  int* counts = (int*)(w + off);   off = alignup(off + (size_t)NN * 4);
  int* rowst  = (int*)(w + off);   off = alignup(off + (size_t)(NN + 1) * 4);
  int* cursor = (int*)(w + off);   off = alignup(off + (size_t)NN * 4);
  int* csrsrc = (int*)(w + off);   off = alignup(off + (size_t)ET * 4);

  // CSR by dst (rebuilt every call; ws is re-poisoned)
  k_init_counts<<<(NN + 255) / 256, 256, 0, stream>>>(counts);
  k_count<<<(EE + 255) / 256, 256, 0, stream>>>(ei, counts);
  k_scan<<<1, 1024, 0, stream>>>(counts, rowst, cursor);
  k_fill<<<(ET + 255) / 256, 256, 0, stream>>>(ei, cursor, csrsrc);

  dim3 gGemm((NN + 63) / 64, HF / 256);
  // layer 1
  k_gemm_xw<<<gGemm, 256, 0, stream>>>(x, W1, Hbuf, NN);
  k_attn<<<NN * NH / 4, 256, 0, stream>>>(Hbuf, as1, ad1, Sbuf, Dbuf);
  k_agg<<<(NN + 3) / 4, 256, 0, stream>>>(Hbuf, Sbuf, Dbuf, rowst, csrsrc, b1, X1);
  // layer 2
  k_gemm_xw<<<gGemm, 256, 0, stream>>>(X1, W2, Hbuf, NN);
  k_attn<<<NN * NH / 4, 256, 0, stream>>>(Hbuf, as2, ad2, Sbuf, Dbuf);
  k_agg<<<(NN + 3) / 4, 256, 0, stream>>>(Hbuf, Sbuf, Dbuf, rowst, csrsrc, b2, X2);
  // classifier + outputs
  k_transpose_wc<<<(OC * 2 * FM + 255) / 256, 256, 0, stream>>>(Wc, WcT);
  k_emb<<<(NN + 63) / 64, 256, 0, stream>>>(X1, X2, WcT, bc, out);
  k_outer<<<dim3((MIRN + 63) / 64, (CIRC + 63) / 64), 256, 0, stream>>>(
      out + OFF_CIRC, out + OFF_MIR, out);
}

// Round 5
// 492.054 us; speedup vs baseline: 1.3105x; 1.3085x over previous
//
#include <hip/hip_runtime.h>
#include <math.h>

constexpr int NN   = 20000;
constexpr int FM   = 128;
constexpr int NH   = 8;
constexpr int HF   = NH * FM;     // 1024
constexpr int EE   = 160000;
constexpr int ET   = EE + NN;     // 180000 (edges + self loops)
constexpr int OC   = 128;
constexpr int CIRC = 504;
constexpr int MIRN = NN - CIRC;   // 19496
constexpr float NEG = 0.2f;

constexpr size_t OFF_CIRC = (size_t)CIRC * MIRN;            // 9,825,984
constexpr size_t OFF_MIR  = OFF_CIRC + (size_t)CIRC * OC;   // 9,890,496

__device__ __forceinline__ float rl_f(float v, int lane) {
  return __uint_as_float(__builtin_amdgcn_readlane(__float_as_uint(v), lane));
}
__device__ __forceinline__ int rl_i(int v, int lane) {
  return __builtin_amdgcn_readlane(v, lane);
}
__device__ __forceinline__ unsigned short bf16_rne(float x) {
  unsigned u = __float_as_uint(x);
  return (unsigned short)((u + 0x7FFFu + ((u >> 16) & 1u)) >> 16);
}
__device__ __forceinline__ float blo(unsigned u) { return __uint_as_float(u << 16); }
__device__ __forceinline__ float bhi(unsigned u) { return __uint_as_float(u & 0xFFFF0000u); }

// ---------------- CSR build ----------------
__global__ void k_init_counts(int* __restrict__ cnt) {
  int i = blockIdx.x * blockDim.x + threadIdx.x;
  if (i < NN) cnt[i] = 1;  // self loop
}

__global__ void k_count(const int* __restrict__ ei, int* __restrict__ cnt) {
  int e = blockIdx.x * blockDim.x + threadIdx.x;
  if (e < EE) atomicAdd(&cnt[ei[EE + e]], 1);
}

__global__ __launch_bounds__(1024) void k_scan(const int* __restrict__ cnt,
                                               int* __restrict__ rs,
                                               int* __restrict__ cur) {
  __shared__ int part[1024];
  const int t = threadIdx.x;
  const int SEG = (NN + 1023) / 1024;  // 20
  int lo = t * SEG, hi = min(NN, lo + SEG);
  int s = 0;
  for (int i = lo; i < hi; ++i) s += cnt[i];
  part[t] = s;
  __syncthreads();
  for (int off = 1; off < 1024; off <<= 1) {
    int v = 0;
    if (t >= off) v = part[t - off];
    __syncthreads();
    part[t] += v;
    __syncthreads();
  }
  int run = (t == 0) ? 0 : part[t - 1];
  for (int i = lo; i < hi; ++i) {
    int c = cnt[i];
    rs[i] = run;
    cur[i] = run;
    run += c;
  }
  if (t == 1023) rs[NN] = part[1023];
}

__global__ void k_fill(const int* __restrict__ ei, int* __restrict__ cur,
                       int* __restrict__ csrc) {
  int i = blockIdx.x * blockDim.x + threadIdx.x;
  if (i >= ET) return;
  int s, d;
  if (i < EE) { s = ei[i]; d = ei[EE + i]; }
  else        { s = i - EE; d = s; }
  int p = atomicAdd(&cur[d], 1);
  csrc[p] = s;
}

// ---- h = X @ W, fused: bf16 H store + fp32 attn dots s,d (k_attn fused) ----
// block tile 64 rows x 256 cols (= 2 heads), 256 threads, 8x8 reg blocking.
__global__ __launch_bounds__(256) void k_gemm_xw(const float* __restrict__ X,
                                                 const float* __restrict__ W,
                                                 const float* __restrict__ Asc,
                                                 const float* __restrict__ Adc,
                                                 unsigned short* __restrict__ H16,
                                                 float* __restrict__ Sv,
                                                 float* __restrict__ Dv,
                                                 int M) {
  __shared__ float xs[64][129];  // pad 129: conflict-free broadcast reads
  const int t = threadIdx.x;
  const int row0 = blockIdx.x * 64;
  const int col0 = blockIdx.y * 256;
#pragma unroll
  for (int it = 0; it < 8; ++it) {
    int f4 = it * 256 + t;      // 2048 float4 = 64x128
    int r = f4 >> 5;
    int c = (f4 & 31) << 2;
    float4 v = make_float4(0.f, 0.f, 0.f, 0.f);
    int gr = row0 + r;
    if (gr < M) v = *reinterpret_cast<const float4*>(X + (size_t)gr * FM + c);
    xs[r][c] = v.x; xs[r][c + 1] = v.y; xs[r][c + 2] = v.z; xs[r][c + 3] = v.w;
  }
  __syncthreads();
  const int tr = (t >> 5) << 3;  // 8 row-groups of 8
  const int tc = (t & 31) << 3;  // 32 col-groups of 8
  float acc[8][8];
#pragma unroll
  for (int r = 0; r < 8; ++r)
#pragma unroll
    for (int c = 0; c < 8; ++c) acc[r][c] = 0.f;
  const float* Wp = W + col0 + tc;
  for (int kk = 0; kk < FM; ++kk) {
    float4 b0 = *reinterpret_cast<const float4*>(Wp + (size_t)kk * HF);
    float4 b1 = *reinterpret_cast<const float4*>(Wp + (size_t)kk * HF + 4);
    float bv[8] = {b0.x, b0.y, b0.z, b0.w, b1.x, b1.y, b1.z, b1.w};
    float av[8];
#pragma unroll
    for (int r = 0; r < 8; ++r) av[r] = xs[tr + r][kk];
#pragma unroll
    for (int r = 0; r < 8; ++r)
#pragma unroll
      for (int c = 0; c < 8; ++c) acc[r][c] += av[r] * bv[c];
  }
  // ---- epilogue 1: bf16 H store ----
#pragma unroll
  for (int r = 0; r < 8; ++r) {
    int gr = row0 + tr + r;
    if (gr < M) {
      union { unsigned short us[8]; uint4 v; } pk;
#pragma unroll
      for (int c = 0; c < 8; ++c) pk.us[c] = bf16_rne(acc[r][c]);
      *reinterpret_cast<uint4*>(H16 + (size_t)gr * HF + col0 + tc) = pk.v;
    }
  }
  // ---- epilogue 2: fp32 attention dots s,d (reduce 16 threads per row,head) ----
  const int hd = 2 * blockIdx.y + ((t & 31) >> 4);  // global head 0..7
  const int fc = (t & 15) << 3;                     // feat offset in head
  float asv[8], adv[8];
#pragma unroll
  for (int c = 0; c < 8; ++c) {
    asv[c] = Asc[hd * FM + fc + c];
    adv[c] = Adc[hd * FM + fc + c];
  }
#pragma unroll
  for (int r = 0; r < 8; ++r) {
    float s = 0.f, d = 0.f;
#pragma unroll
    for (int c = 0; c < 8; ++c) {
      s += acc[r][c] * asv[c];
      d += acc[r][c] * adv[c];
    }
#pragma unroll
    for (int mo = 1; mo <= 8; mo <<= 1) {
      s += __shfl_xor(s, mo, 64);
      d += __shfl_xor(d, mo, 64);
    }
    int gr = row0 + tr + r;
    if ((t & 15) == 0 && gr < M) {
      Sv[gr * 8 + hd] = s;
      Dv[gr * 8 + hd] = d;
    }
  }
}

// ---------------- per-dst online-softmax aggregation (1 wave / node) -------
// softmax lanes: (edge j = lane>>3, head h = lane&7); gather: bf16 rows,
// lane covers heads (lane>>4, +4) x feats [(lane&15)*8, +8).
__global__ __launch_bounds__(256) void k_agg(const unsigned short* __restrict__ H16,
                                             const float* __restrict__ Sv,
                                             const float* __restrict__ Dv,
                                             const int* __restrict__ rs,
                                             const int* __restrict__ csrc,
                                             const float* __restrict__ bias,
                                             float* __restrict__ Xo) {
  const int wave = threadIdx.x >> 6;
  const int lane = threadIdx.x & 63;
  const int n = blockIdx.x * 4 + wave;
  if (n >= NN) return;
  const int r0 = rs[n];
  const int deg = rs[n + 1] - r0;   // >= 1 (self loop)
  const int j = lane >> 3, h = lane & 7;
  const int h0 = lane >> 4;         // 0..3
  const int boff = h0 * FM + (lane & 15) * 8;  // ushort offset of load0
  const float dvh = Dv[n * 8 + h];

  float m = -INFINITY, l = 0.f;
  float4 acc[4];  // [0..1]: head h0 feats 8; [2..3]: head h0+4 feats 8
#pragma unroll
  for (int q = 0; q < 4; ++q) acc[q] = make_float4(0.f, 0.f, 0.f, 0.f);

  for (int base = 0; base < deg; base += 8) {
    const int cnt = deg - base;
    int sj = csrc[r0 + min(base + j, deg - 1)];
    float lg = (j < cnt) ? (Sv[sj * 8 + h] + dvh) : -INFINITY;
    lg = lg > 0.f ? lg : NEG * lg;
    float cm = lg;
    cm = fmaxf(cm, __shfl_xor(cm, 8, 64));
    cm = fmaxf(cm, __shfl_xor(cm, 16, 64));
    cm = fmaxf(cm, __shfl_xor(cm, 32, 64));
    float mn = fmaxf(m, cm);
    float fs = expf(m - mn);     // first chunk: exp(-inf)=0
    float p = expf(lg - mn);     // inactive: exp(-inf)=0
    float cs = p;
    cs += __shfl_xor(cs, 8, 64);
    cs += __shfl_xor(cs, 16, 64);
    cs += __shfl_xor(cs, 32, 64);
    l = l * fs + cs;
    m = mn;
    float f0 = __shfl(fs, h0, 64);      // fs of head h0 (lives in lane h0)
    float f1 = __shfl(fs, h0 + 4, 64);  // fs of head h0+4
    acc[0].x *= f0; acc[0].y *= f0; acc[0].z *= f0; acc[0].w *= f0;
    acc[1].x *= f0; acc[1].y *= f0; acc[1].z *= f0; acc[1].w *= f0;
    acc[2].x *= f1; acc[2].y *= f1; acc[2].z *= f1; acc[2].w *= f1;
    acc[3].x *= f1; acc[3].y *= f1; acc[3].z *= f1; acc[3].w *= f1;
#pragma unroll
    for (int jj = 0; jj < 8; ++jj) {
      if (jj < cnt) {
        int se = rl_i(sj, jj * 8);
        const uint4* hp = reinterpret_cast<const uint4*>(H16 + (size_t)se * HF + boff);
        uint4 v0 = hp[0];
        uint4 v1 = hp[64];  // +64 uint4 = +512 ushorts = head h0+4
        float pe0 = __shfl(p, jj * 8 + h0, 64);
        float pe1 = __shfl(p, jj * 8 + h0 + 4, 64);
        acc[0].x += pe0 * blo(v0.x); acc[0].y += pe0 * bhi(v0.x);
        acc[0].z += pe0 * blo(v0.y); acc[0].w += pe0 * bhi(v0.y);
        acc[1].x += pe0 * blo(v0.z); acc[1].y += pe0 * bhi(v0.z);
        acc[1].z += pe0 * blo(v0.w); acc[1].w += pe0 * bhi(v0.w);
        acc[2].x += pe1 * blo(v1.x); acc[2].y += pe1 * bhi(v1.x);
        acc[2].z += pe1 * blo(v1.y); acc[2].w += pe1 * bhi(v1.y);
        acc[3].x += pe1 * blo(v1.z); acc[3].y += pe1 * bhi(v1.z);
        acc[3].z += pe1 * blo(v1.w); acc[3].w += pe1 * bhi(v1.w);
      }
    }
  }
  // divide by per-head denom, sum over heads (xor 16/32 folds head groups)
  float inv0 = 1.0f / (__shfl(l, h0, 64) + 1e-16f);
  float inv1 = 1.0f / (__shfl(l, h0 + 4, 64) + 1e-16f);
  float o[8];
  o[0] = acc[0].x * inv0 + acc[2].x * inv1;
  o[1] = acc[0].y * inv0 + acc[2].y * inv1;
  o[2] = acc[0].z * inv0 + acc[2].z * inv1;
  o[3] = acc[0].w * inv0 + acc[2].w * inv1;
  o[4] = acc[1].x * inv0 + acc[3].x * inv1;
  o[5] = acc[1].y * inv0 + acc[3].y * inv1;
  o[6] = acc[1].z * inv0 + acc[3].z * inv1;
  o[7] = acc[1].w * inv0 + acc[3].w * inv1;
#pragma unroll
  for (int k = 0; k < 8; ++k) {
    o[k] += __shfl_xor(o[k], 16, 64);
    o[k] += __shfl_xor(o[k], 32, 64);
  }
  if (lane < 16) {
    const int f0i = lane * 8;
    float4 b0 = *reinterpret_cast<const float4*>(bias + f0i);
    float4 b1 = *reinterpret_cast<const float4*>(bias + f0i + 4);
    float4 w0, w1;
    w0.x = fmaxf(o[0] * 0.125f + b0.x, 0.f);
    w0.y = fmaxf(o[1] * 0.125f + b0.y, 0.f);
    w0.z = fmaxf(o[2] * 0.125f + b0.z, 0.f);
    w0.w = fmaxf(o[3] * 0.125f + b0.w, 0.f);
    w1.x = fmaxf(o[4] * 0.125f + b1.x, 0.f);
    w1.y = fmaxf(o[5] * 0.125f + b1.y, 0.f);
    w1.z = fmaxf(o[6] * 0.125f + b1.z, 0.f);
    w1.w = fmaxf(o[7] * 0.125f + b1.w, 0.f);
    *reinterpret_cast<float4*>(Xo + (size_t)n * FM + f0i) = w0;
    *reinterpret_cast<float4*>(Xo + (size_t)n * FM + f0i + 4) = w1;
  }
}

// ---------------- Wc transpose: WcT[c*128+k][o] = Wc[o][c][k] ----------------
__global__ void k_transpose_wc(const float* __restrict__ Wc, float* __restrict__ WcT) {
  int i = blockIdx.x * blockDim.x + threadIdx.x;
  if (i < OC * 2 * FM) {
    int o = i / (2 * FM), k = i % (2 * FM);
    WcT[k * OC + o] = Wc[i];
  }
}

// ---------------- emb = [x1|x2] @ WcT + bc; write circ/mir slices of out ----
__global__ __launch_bounds__(256) void k_emb(const float* __restrict__ X1,
                                             const float* __restrict__ X2,
                                             const float* __restrict__ WcT,
                                             const float* __restrict__ bc,
                                             float* __restrict__ Out) {
  __shared__ float xs[64][129];
  const int t = threadIdx.x;
  const int row0 = blockIdx.x * 64;
  const int tr = (t >> 5) << 3;  // 8 rows
  const int tc = (t & 31) << 2;  // 4 cols
  float acc[8][4] = {};
  for (int half = 0; half < 2; ++half) {
    const float* Xs = half ? X2 : X1;
    __syncthreads();  // protect xs reuse across halves
#pragma unroll
    for (int it = 0; it < 8; ++it) {
      int f4 = it * 256 + t;  // 2048 float4 = 64 x 128
      int r = f4 >> 5;
      int c = (f4 & 31) << 2;
      int gr = row0 + r;
      float4 v = make_float4(0.f, 0.f, 0.f, 0.f);
      if (gr < NN) v = *reinterpret_cast<const float4*>(Xs + (size_t)gr * FM + c);
      xs[r][c] = v.x; xs[r][c + 1] = v.y; xs[r][c + 2] = v.z; xs[r][c + 3] = v.w;
    }
    __syncthreads();
    const float* Wp = WcT + (size_t)half * FM * OC;
    for (int kk = 0; kk < FM; ++kk) {
      float4 b = *reinterpret_cast<const float4*>(Wp + kk * OC + tc);
      float av[8];
#pragma unroll
      for (int r = 0; r < 8; ++r) av[r] = xs[tr + r][kk];
#pragma unroll
      for (int r = 0; r < 8; ++r) {
        acc[r][0] += av[r] * b.x;
        acc[r][1] += av[r] * b.y;
        acc[r][2] += av[r] * b.z;
        acc[r][3] += av[r] * b.w;
      }
    }
  }
  float4 bcv = *reinterpret_cast<const float4*>(bc + tc);
#pragma unroll
  for (int r = 0; r < 8; ++r) {
    int gr = row0 + tr + r;
    if (gr < NN) {
      float4 o;
      o.x = acc[r][0] + bcv.x;
      o.y = acc[r][1] + bcv.y;
      o.z = acc[r][2] + bcv.z;
      o.w = acc[r][3] + bcv.w;
      float* dst = (gr < CIRC)
                       ? (Out + OFF_CIRC + (size_t)gr * OC + tc)
                       : (Out + OFF_MIR + (size_t)(gr - CIRC) * OC + tc);
      *reinterpret_cast<float4*>(dst) = o;
    }
  }
}

// ---------------- out1 = circ @ mir.T (504 x 19496, K=128) ----------------
__global__ __launch_bounds__(256) void k_outer(const float* __restrict__ A,
                                               const float* __restrict__ B,
                                               float* __restrict__ C) {
  __shared__ float As[64][65];
  __shared__ float Bs[64][65];
  const int t = threadIdx.x;
  const int i0 = blockIdx.y * 64;
  const int j0 = blockIdx.x * 64;
  const int tx = t & 15, ty = t >> 4;
  float acc[4][4] = {};
  for (int kh = 0; kh < 2; ++kh) {
    __syncthreads();
#pragma unroll
    for (int it = 0; it < 4; ++it) {
      int f4 = it * 256 + t;   // 1024 float4 = 64 rows x 16
      int r = f4 >> 4;
      int c = (f4 & 15) << 2;
      float4 v = make_float4(0.f, 0.f, 0.f, 0.f);
      if (i0 + r < CIRC)
        v = *reinterpret_cast<const float4*>(A + (size_t)(i0 + r) * OC + kh * 64 + c);
      As[r][c] = v.x; As[r][c + 1] = v.y; As[r][c + 2] = v.z; As[r][c + 3] = v.w;
      float4 w = make_float4(0.f, 0.f, 0.f, 0.f);
      if (j0 + r < MIRN)
        w = *reinterpret_cast<const float4*>(B + (size_t)(j0 + r) * OC + kh * 64 + c);
      Bs[r][c] = w.x; Bs[r][c + 1] = w.y; Bs[r][c + 2] = w.z; Bs[r][c + 3] = w.w;
    }
    __syncthreads();
    for (int kk = 0; kk < 64; ++kk) {
      float a[4], b[4];
#pragma unroll
      for (int r = 0; r < 4; ++r) a[r] = As[ty * 4 + r][kk];
#pragma unroll
      for (int c = 0; c < 4; ++c) b[c] = Bs[tx * 4 + c][kk];
#pragma unroll
      for (int r = 0; r < 4; ++r)
#pragma unroll
        for (int c = 0; c < 4; ++c) acc[r][c] += a[r] * b[c];
    }
  }
#pragma unroll
  for (int r = 0; r < 4; ++r) {
    int i = i0 + ty * 4 + r;
    if (i >= CIRC) break;
#pragma unroll
    for (int c = 0; c < 4; ++c) {
      int j = j0 + tx * 4 + c;
      if (j < MIRN) C[(size_t)i * MIRN + j] = acc[r][c];
    }
  }
}

// ---------------- launcher ----------------
static inline size_t alignup(size_t v) { return (v + 255) & ~(size_t)255; }

extern "C" void kernel_launch(void* const* d_in, const int* in_sizes, int n_in,
                              void* d_out, int out_size, void* d_ws, size_t ws_size,
                              hipStream_t stream) {
  const float* x   = (const float*)d_in[0];
  const int*   ei  = (const int*)d_in[1];
  const float* W1  = (const float*)d_in[2];
  const float* as1 = (const float*)d_in[3];
  const float* ad1 = (const float*)d_in[4];
  const float* b1  = (const float*)d_in[5];
  const float* W2  = (const float*)d_in[6];
  const float* as2 = (const float*)d_in[7];
  const float* ad2 = (const float*)d_in[8];
  const float* b2  = (const float*)d_in[9];
  const float* Wc  = (const float*)d_in[10];
  const float* bc  = (const float*)d_in[11];
  float* out = (float*)d_out;

  char* w = (char*)d_ws;
  size_t off = 0;
  unsigned short* H16 = (unsigned short*)(w + off); off = alignup(off + (size_t)NN * HF * 2);
  float* Sbuf = (float*)(w + off); off = alignup(off + (size_t)NN * NH * 4);
  float* Dbuf = (float*)(w + off); off = alignup(off + (size_t)NN * NH * 4);
  float* X1   = (float*)(w + off); off = alignup(off + (size_t)NN * FM * 4);
  float* X2   = (float*)(w + off); off = alignup(off + (size_t)NN * FM * 4);
  float* WcT  = (float*)(w + off); off = alignup(off + (size_t)OC * 2 * FM * 4);
  int* counts = (int*)(w + off);   off = alignup(off + (size_t)NN * 4);
  int* rowst  = (int*)(w + off);   off = alignup(off + (size_t)(NN + 1) * 4);
  int* cursor = (int*)(w + off);   off = alignup(off + (size_t)NN * 4);
  int* csrsrc = (int*)(w + off);   off = alignup(off + (size_t)ET * 4);

  // CSR by dst (rebuilt every call; ws is re-poisoned)
  k_init_counts<<<(NN + 255) / 256, 256, 0, stream>>>(counts);
  k_count<<<(EE + 255) / 256, 256, 0, stream>>>(ei, counts);
  k_scan<<<1, 1024, 0, stream>>>(counts, rowst, cursor);
  k_fill<<<(ET + 255) / 256, 256, 0, stream>>>(ei, cursor, csrsrc);

  dim3 gGemm((NN + 63) / 64, HF / 256);
  // layer 1 (gemm fuses bf16-H store + fp32 attn dots)
  k_gemm_xw<<<gGemm, 256, 0, stream>>>(x, W1, as1, ad1, H16, Sbuf, Dbuf, NN);
  k_agg<<<(NN + 3) / 4, 256, 0, stream>>>(H16, Sbuf, Dbuf, rowst, csrsrc, b1, X1);
  // layer 2
  k_gemm_xw<<<gGemm, 256, 0, stream>>>(X1, W2, as2, ad2, H16, Sbuf, Dbuf, NN);
  k_agg<<<(NN + 3) / 4, 256, 0, stream>>>(H16, Sbuf, Dbuf, rowst, csrsrc, b2, X2);
  // classifier + outputs
  k_transpose_wc<<<(OC * 2 * FM + 255) / 256, 256, 0, stream>>>(Wc, WcT);
  k_emb<<<(NN + 63) / 64, 256, 0, stream>>>(X1, X2, WcT, bc, out);
  k_outer<<<dim3((MIRN + 63) / 64, (CIRC + 63) / 64), 256, 0, stream>>>(
      out + OFF_CIRC, out + OFF_MIR, out);
}